// Round 1
// baseline (113.399 us; speedup 1.0000x reference)
//
#include <hip/hip_runtime.h>
#include <math.h>

#define N 384
#define DF 128
#define TEMP 2.0f
#define SOFT_LAMBDA 0.5f
#define BETA 1.0f
#define EPS_COS 1e-8f
#define EPS_LOG 1e-7f

// Block i computes row i of all pairwise quantities into LDS, then the O(n^2)
// rank-denominator loop for that row, then reduces to per-row partial sums.
// NOTE: logits = -dist/TEMP <= 0 with diagonal exactly 0 => row max is exactly
// 0, so the reference's max-subtraction is a no-op and is skipped.
__global__ __launch_bounds__(N) void rnc_main(
    const float* __restrict__ feat,   // [N, DF]
    const float* __restrict__ rg,     // [N, 3]
    const float* __restrict__ rr,     // [N, 3]
    const float* __restrict__ tr,     // [N, 3]
    const int*   __restrict__ sym,    // [N]
    float* __restrict__ partial_h,    // [N]
    float* __restrict__ partial_t)    // [N]
{
    const int i = blockIdx.x;
    const int j = threadIdx.x;

    __shared__ __align__(16) float fi[DF];
    __shared__ __align__(16) float td_s[N];
    __shared__ __align__(16) float rd_s[N];
    __shared__ __align__(16) float eo_s[N];
    __shared__ float red_h[N / 64];
    __shared__ float red_t[N / 64];
    __shared__ float hdr[12];  // trans_i[3], rg_i[3], |rg_i|, rr_i[3], |rr_i|, sym_i

    if (j < DF) fi[j] = feat[i * DF + j];
    if (j == 0) {
        hdr[0] = tr[i * 3 + 0];
        hdr[1] = tr[i * 3 + 1];
        hdr[2] = tr[i * 3 + 2];
        float g0 = rg[i * 3 + 0], g1 = rg[i * 3 + 1], g2 = rg[i * 3 + 2];
        hdr[3] = g0; hdr[4] = g1; hdr[5] = g2;
        hdr[6] = fmaxf(sqrtf(g0 * g0 + g1 * g1 + g2 * g2), EPS_COS);
        float r0 = rr[i * 3 + 0], r1 = rr[i * 3 + 1], r2 = rr[i * 3 + 2];
        hdr[7] = r0; hdr[8] = r1; hdr[9] = r2;
        hdr[10] = fmaxf(sqrtf(r0 * r0 + r1 * r1 + r2 * r2), EPS_COS);
        hdr[11] = (sym[i] == 1) ? 1.0f : 0.0f;
    }
    __syncthreads();

    // ---- feature L2 distance (zero-safe) -> logit lo_j, exp eo_j ----
    const float4* fj4 = reinterpret_cast<const float4*>(feat + j * DF);
    const float4* fi4 = reinterpret_cast<const float4*>(fi);
    float sq = 0.f;
#pragma unroll
    for (int d = 0; d < DF / 4; ++d) {
        float4 a = fi4[d];
        float4 b = fj4[d];
        float dx = a.x - b.x, dy = a.y - b.y, dz = a.z - b.z, dw = a.w - b.w;
        sq += dx * dx + dy * dy + dz * dz + dw * dw;
    }
    float dist = (sq > 0.f) ? sqrtf(sq) : 0.f;
    float lo_j = -dist / TEMP;
    float eo_j = expf(lo_j);

    // ---- trans smooth-L1 mean over 3 coords ----
    float td_j;
    {
        float s = 0.f;
#pragma unroll
        for (int c = 0; c < 3; ++c) {
            float d_ = hdr[c] - tr[j * 3 + c];
            float ad = fabsf(d_);
            s += (ad < BETA) ? (0.5f * d_ * d_ / BETA) : (ad - 0.5f * BETA);
        }
        td_j = s * (1.0f / 3.0f);
    }

    // ---- rot cosine diffs ----
    float gdiff, rdiff;
    {
        float g0 = rg[j * 3 + 0], g1 = rg[j * 3 + 1], g2 = rg[j * 3 + 2];
        float nj = fmaxf(sqrtf(g0 * g0 + g1 * g1 + g2 * g2), EPS_COS);
        float dot = hdr[3] * g0 + hdr[4] * g1 + hdr[5] * g2;
        gdiff = 1.0f - dot / (hdr[6] * nj);
    }
    {
        float r0 = rr[j * 3 + 0], r1 = rr[j * 3 + 1], r2 = rr[j * 3 + 2];
        float nj = fmaxf(sqrtf(r0 * r0 + r1 * r1 + r2 * r2), EPS_COS);
        float dot = hdr[7] * r0 + hdr[8] * r1 + hdr[9] * r2;
        rdiff = 1.0f - dot / (hdr[10] * nj);
    }
    bool pair_sym = (hdr[11] != 0.0f) || (sym[j] == 1);
    float rd_j = pair_sym ? gdiff : (gdiff + rdiff);

    td_s[j] = td_j;
    rd_s[j] = rd_j;
    eo_s[j] = (j == i) ? 0.0f : eo_j;  // exclude diagonal k from denominators
    __syncthreads();

    // ---- rank denominators: den[j] = sum_k eo[k] * mask ----
    float den_t = 0.f, den_h = 0.f;
    const float4* td4 = reinterpret_cast<const float4*>(td_s);
    const float4* rd4 = reinterpret_cast<const float4*>(rd_s);
    const float4* eo4 = reinterpret_cast<const float4*>(eo_s);
    for (int k4 = 0; k4 < N / 4; ++k4) {
        float4 t = td4[k4];
        float4 rv = rd4[k4];
        float4 e = eo4[k4];
        {
            bool mt = (t.x >= td_j);
            den_t += mt ? e.x : 0.f;
            den_h += (mt && rv.x >= rd_j) ? e.x : 0.f;
        }
        {
            bool mt = (t.y >= td_j);
            den_t += mt ? e.y : 0.f;
            den_h += (mt && rv.y >= rd_j) ? e.y : 0.f;
        }
        {
            bool mt = (t.z >= td_j);
            den_t += mt ? e.z : 0.f;
            den_h += (mt && rv.z >= rd_j) ? e.z : 0.f;
        }
        {
            bool mt = (t.w >= td_j);
            den_t += mt ? e.w : 0.f;
            den_h += (mt && rv.w >= rd_j) ? e.w : 0.f;
        }
    }

    float pos_h = 0.f, pos_t = 0.f;
    if (j != i) {
        pos_h = lo_j - logf(den_h + EPS_LOG);
        pos_t = lo_j - logf(den_t + EPS_LOG);
    }

    // ---- block reduction (384 threads = 6 waves) ----
#pragma unroll
    for (int off = 32; off > 0; off >>= 1) {
        pos_h += __shfl_down(pos_h, off, 64);
        pos_t += __shfl_down(pos_t, off, 64);
    }
    int wave = j >> 6, lane = j & 63;
    if (lane == 0) {
        red_h[wave] = pos_h;
        red_t[wave] = pos_t;
    }
    __syncthreads();
    if (j == 0) {
        float sh = 0.f, st = 0.f;
#pragma unroll
        for (int w = 0; w < N / 64; ++w) {
            sh += red_h[w];
            st += red_t[w];
        }
        partial_h[i] = sh;
        partial_t[i] = st;
    }
}

__global__ __launch_bounds__(N) void rnc_final(
    const float* __restrict__ partial_h,
    const float* __restrict__ partial_t,
    float* __restrict__ out)
{
    int j = threadIdx.x;
    float h = partial_h[j];
    float t = partial_t[j];
#pragma unroll
    for (int off = 32; off > 0; off >>= 1) {
        h += __shfl_down(h, off, 64);
        t += __shfl_down(t, off, 64);
    }
    __shared__ float rh[N / 64];
    __shared__ float rt[N / 64];
    int wave = j >> 6, lane = j & 63;
    if (lane == 0) {
        rh[wave] = h;
        rt[wave] = t;
    }
    __syncthreads();
    if (j == 0) {
        double sh = 0.0, st = 0.0;
#pragma unroll
        for (int w = 0; w < N / 64; ++w) {
            sh += (double)rh[w];
            st += (double)rt[w];
        }
        const double denom = (double)N * (double)(N - 1);
        out[0] = (float)(-(sh + (double)SOFT_LAMBDA * st) / denom);
    }
}

extern "C" void kernel_launch(void* const* d_in, const int* in_sizes, int n_in,
                              void* d_out, int out_size, void* d_ws, size_t ws_size,
                              hipStream_t stream) {
    const float* feat = (const float*)d_in[0];  // [384,128]
    const float* rg   = (const float*)d_in[1];  // [384,3]
    const float* rr   = (const float*)d_in[2];  // [384,3]
    const float* tr   = (const float*)d_in[3];  // [384,3]
    const int*   sym  = (const int*)d_in[4];    // [384,1]
    float* out = (float*)d_out;

    float* partial_h = (float*)d_ws;
    float* partial_t = partial_h + N;

    rnc_main<<<N, N, 0, stream>>>(feat, rg, rr, tr, sym, partial_h, partial_t);
    rnc_final<<<1, N, 0, stream>>>(partial_h, partial_t, out);
}

// Round 2
// 93.446 us; speedup vs baseline: 1.2135x; 1.2135x over previous
//
#include <hip/hip_runtime.h>
#include <math.h>

#define N 384
#define HB 192   // j-coverage per block (half a row)
#define DF 128
#define TEMP 2.0f
#define SOFT_LAMBDA 0.5f
#define BETA 1.0f
#define EPS_COS 1e-8f
#define EPS_LOG 1e-7f

// Grid = 768 blocks: block b handles row i = b>>1, j-half h = b&1.
// Block = 192 threads = 3 waves.
// Stage 1: each thread computes pairwise quantities for 2 elements (all 384 k
//   needed for the denominators) -> pk[k] = {td, rd, eo (0 on diag), lo}.
// Stage 2: wave kg (=t/64) covers k in [kg*128, kg*128+128); lane l holds 3 j's
//   (j = h*192 + l*3 + jj) with td/rd in registers -> 18 VALU ops per one
//   broadcast ds_read_b128. Partial dens reduced across the 3 waves via LDS.
// Stage 3: per-j pos terms, block reduction, per-block partial out.
// NOTE: logits <= 0 with exact 0 on the diagonal => row-max subtraction in the
// reference is a provable no-op and is skipped.
__global__ __launch_bounds__(192) void rnc_main(
    const float* __restrict__ feat,   // [N, DF]
    const float* __restrict__ rg,     // [N, 3]
    const float* __restrict__ rr,     // [N, 3]
    const float* __restrict__ tr,     // [N, 3]
    const int*   __restrict__ sym,    // [N]
    float* __restrict__ partial_h,    // [2N]
    float* __restrict__ partial_t)    // [2N]
{
    const int i = blockIdx.x >> 1;
    const int h = blockIdx.x & 1;
    const int t = threadIdx.x;

    __shared__ __align__(16) float4 pk[N];      // td, rd, eo, lo
    __shared__ __align__(16) float2 dp[HB][4];  // [j_local][kg] partial (den_t, den_h)
    __shared__ __align__(16) float fi[DF];
    __shared__ float hdr[12];
    __shared__ float red_h[3], red_t[3];

    if (t < DF) fi[t] = feat[i * DF + t];
    if (t == 0) {
        hdr[0] = tr[i * 3 + 0];
        hdr[1] = tr[i * 3 + 1];
        hdr[2] = tr[i * 3 + 2];
        float g0 = rg[i * 3 + 0], g1 = rg[i * 3 + 1], g2 = rg[i * 3 + 2];
        hdr[3] = g0; hdr[4] = g1; hdr[5] = g2;
        hdr[6] = fmaxf(sqrtf(g0 * g0 + g1 * g1 + g2 * g2), EPS_COS);
        float r0 = rr[i * 3 + 0], r1 = rr[i * 3 + 1], r2 = rr[i * 3 + 2];
        hdr[7] = r0; hdr[8] = r1; hdr[9] = r2;
        hdr[10] = fmaxf(sqrtf(r0 * r0 + r1 * r1 + r2 * r2), EPS_COS);
        hdr[11] = (sym[i] == 1) ? 1.0f : 0.0f;
    }
    __syncthreads();

    // ---- stage 1: pairwise quantities for elements t and t+192 ----
    for (int e = t; e < N; e += HB) {
        const float4* fj4 = reinterpret_cast<const float4*>(feat + e * DF);
        const float4* fi4 = reinterpret_cast<const float4*>(fi);
        float sq = 0.f;
#pragma unroll 8
        for (int d = 0; d < DF / 4; ++d) {
            float4 a = fi4[d];
            float4 b = fj4[d];
            float dx = a.x - b.x, dy = a.y - b.y, dz = a.z - b.z, dw = a.w - b.w;
            sq += dx * dx + dy * dy + dz * dz + dw * dw;
        }
        float dist = (sq > 0.f) ? sqrtf(sq) : 0.f;
        float lo = -dist * (1.0f / TEMP);
        float eo = (e == i) ? 0.f : expf(lo);

        float s = 0.f;
#pragma unroll
        for (int c = 0; c < 3; ++c) {
            float d_ = hdr[c] - tr[e * 3 + c];
            float ad = fabsf(d_);
            s += (ad < BETA) ? (0.5f * d_ * d_ / BETA) : (ad - 0.5f * BETA);
        }
        float td = s * (1.0f / 3.0f);

        float g0 = rg[e * 3 + 0], g1 = rg[e * 3 + 1], g2 = rg[e * 3 + 2];
        float ng = fmaxf(sqrtf(g0 * g0 + g1 * g1 + g2 * g2), EPS_COS);
        float gdiff = 1.0f - (hdr[3] * g0 + hdr[4] * g1 + hdr[5] * g2) / (hdr[6] * ng);
        float r0 = rr[e * 3 + 0], r1 = rr[e * 3 + 1], r2 = rr[e * 3 + 2];
        float nr = fmaxf(sqrtf(r0 * r0 + r1 * r1 + r2 * r2), EPS_COS);
        float rdiff = 1.0f - (hdr[7] * r0 + hdr[8] * r1 + hdr[9] * r2) / (hdr[10] * nr);
        bool pair_sym = (hdr[11] != 0.0f) || (sym[e] == 1);
        float rd = pair_sym ? gdiff : (gdiff + rdiff);

        pk[e] = make_float4(td, rd, eo, lo);
    }
    __syncthreads();

    // ---- stage 2: rank denominators, j-tiled x3, k split over 3 waves ----
    const int kg = t >> 6;       // wave id 0..2 -> k chunk
    const int l  = t & 63;
    const int jl = l * 3;        // local j base (0..189)
    float tdj[3], rdj[3];
    float dent[3] = {0.f, 0.f, 0.f};
    float denh[3] = {0.f, 0.f, 0.f};
#pragma unroll
    for (int jj = 0; jj < 3; ++jj) {
        float4 p = pk[h * HB + jl + jj];
        tdj[jj] = p.x;
        rdj[jj] = p.y;
    }
    const int k0 = kg * (N / 3);
#pragma unroll 4
    for (int k = k0; k < k0 + N / 3; ++k) {
        float4 p = pk[k];  // wave-uniform -> broadcast, conflict-free
#pragma unroll
        for (int jj = 0; jj < 3; ++jj) {
            bool mt = p.x >= tdj[jj];
            bool mh = mt && (p.y >= rdj[jj]);
            dent[jj] += mt ? p.z : 0.f;
            denh[jj] += mh ? p.z : 0.f;
        }
    }
#pragma unroll
    for (int jj = 0; jj < 3; ++jj) dp[jl + jj][kg] = make_float2(dent[jj], denh[jj]);
    __syncthreads();

    // ---- stage 3: per-j pos terms (thread t <-> j_local t), block reduce ----
    float st_ = 0.f, sh_ = 0.f;
#pragma unroll
    for (int g = 0; g < 3; ++g) {
        float2 v = dp[t][g];
        st_ += v.x;
        sh_ += v.y;
    }
    const int j = h * HB + t;
    float pos_h = 0.f, pos_t = 0.f;
    if (j != i) {
        float lo = pk[j].w;
        pos_h = lo - logf(sh_ + EPS_LOG);
        pos_t = lo - logf(st_ + EPS_LOG);
    }
#pragma unroll
    for (int off = 32; off > 0; off >>= 1) {
        pos_h += __shfl_down(pos_h, off, 64);
        pos_t += __shfl_down(pos_t, off, 64);
    }
    if (l == 0) {
        red_h[kg] = pos_h;
        red_t[kg] = pos_t;
    }
    __syncthreads();
    if (t == 0) {
        partial_h[blockIdx.x] = red_h[0] + red_h[1] + red_h[2];
        partial_t[blockIdx.x] = red_t[0] + red_t[1] + red_t[2];
    }
}

__global__ __launch_bounds__(768) void rnc_final(
    const float* __restrict__ partial_h,
    const float* __restrict__ partial_t,
    float* __restrict__ out)
{
    const int t = threadIdx.x;
    float hsum = partial_h[t];
    float tsum = partial_t[t];
#pragma unroll
    for (int off = 32; off > 0; off >>= 1) {
        hsum += __shfl_down(hsum, off, 64);
        tsum += __shfl_down(tsum, off, 64);
    }
    __shared__ float rh[12], rt[12];
    const int wave = t >> 6, lane = t & 63;
    if (lane == 0) {
        rh[wave] = hsum;
        rt[wave] = tsum;
    }
    __syncthreads();
    if (t == 0) {
        double sh = 0.0, st = 0.0;
#pragma unroll
        for (int w = 0; w < 12; ++w) {
            sh += (double)rh[w];
            st += (double)rt[w];
        }
        const double denom = (double)N * (double)(N - 1);
        out[0] = (float)(-(sh + (double)SOFT_LAMBDA * st) / denom);
    }
}

extern "C" void kernel_launch(void* const* d_in, const int* in_sizes, int n_in,
                              void* d_out, int out_size, void* d_ws, size_t ws_size,
                              hipStream_t stream) {
    const float* feat = (const float*)d_in[0];  // [384,128]
    const float* rg   = (const float*)d_in[1];  // [384,3]
    const float* rr   = (const float*)d_in[2];  // [384,3]
    const float* tr   = (const float*)d_in[3];  // [384,3]
    const int*   sym  = (const int*)d_in[4];    // [384,1]
    float* out = (float*)d_out;

    float* partial_h = (float*)d_ws;        // [768]
    float* partial_t = partial_h + 2 * N;   // [768]

    rnc_main<<<2 * N, HB, 0, stream>>>(feat, rg, rr, tr, sym, partial_h, partial_t);
    rnc_final<<<1, 2 * N, 0, stream>>>(partial_h, partial_t, out);
}

// Round 3
// 79.812 us; speedup vs baseline: 1.4208x; 1.1708x over previous
//
#include <hip/hip_runtime.h>
#include <math.h>

#define N 384
#define DF 128
#define TI 16
#define TK 16
#define TEMP 2.0f
#define SOFT_LAMBDA 0.5f
#define BETA 1.0f
#define EPS_COS 1e-8f
#define EPS_LOG 1e-7f

// ---------------------------------------------------------------------------
// Kernel A: pairwise table pk[i][k] = {td, rd, eo (0 on diag), lo}.
// 24x24 blocks of 16x16 pairs, 256 threads. Feature rows staged in LDS
// (rows padded to 33 float4 = stride 132 floats to break bank alignment).
// GEMM-shaped: high occupancy, all latency well hidden.
// ---------------------------------------------------------------------------
__global__ __launch_bounds__(256) void rnc_pairs(
    const float* __restrict__ feat,   // [N, DF]
    const float* __restrict__ rg,     // [N, 3]
    const float* __restrict__ rr,     // [N, 3]
    const float* __restrict__ tr,     // [N, 3]
    const int*   __restrict__ sym,    // [N]
    float4* __restrict__ pk)          // [N*N]
{
    const int i0 = blockIdx.y * TI;
    const int k0 = blockIdx.x * TK;
    const int t = threadIdx.x;

    __shared__ __align__(16) float4 fi_s[TI][DF / 4 + 1];  // +1 f4 pad
    __shared__ __align__(16) float4 fk_s[TK][DF / 4 + 1];
    __shared__ float4 hi_s[TI], gi_s[TI], ri_s[TI];  // trans+sym, rg+norm, rr+norm
    __shared__ float4 hk_s[TK], gk_s[TK], rk_s[TK];

    if (t < TI) {
        int g = i0 + t;
        hi_s[t] = make_float4(tr[g * 3], tr[g * 3 + 1], tr[g * 3 + 2],
                              (sym[g] == 1) ? 1.f : 0.f);
        float a = rg[g * 3], b = rg[g * 3 + 1], c = rg[g * 3 + 2];
        gi_s[t] = make_float4(a, b, c, fmaxf(sqrtf(a * a + b * b + c * c), EPS_COS));
        float d = rr[g * 3], e = rr[g * 3 + 1], f = rr[g * 3 + 2];
        ri_s[t] = make_float4(d, e, f, fmaxf(sqrtf(d * d + e * e + f * f), EPS_COS));
    } else if (t >= 32 && t < 32 + TK) {
        int g = k0 + (t - 32);
        int tl = t - 32;
        hk_s[tl] = make_float4(tr[g * 3], tr[g * 3 + 1], tr[g * 3 + 2],
                               (sym[g] == 1) ? 1.f : 0.f);
        float a = rg[g * 3], b = rg[g * 3 + 1], c = rg[g * 3 + 2];
        gk_s[tl] = make_float4(a, b, c, fmaxf(sqrtf(a * a + b * b + c * c), EPS_COS));
        float d = rr[g * 3], e = rr[g * 3 + 1], f = rr[g * 3 + 2];
        rk_s[tl] = make_float4(d, e, f, fmaxf(sqrtf(d * d + e * e + f * f), EPS_COS));
    }

    const float4* feat4 = reinterpret_cast<const float4*>(feat);
#pragma unroll
    for (int idx = 0; idx < 2; ++idx) {
        int u = t + idx * 256;            // 0..511 over 16 rows x 32 f4
        int row = u >> 5, c = u & 31;
        fi_s[row][c] = feat4[(i0 + row) * (DF / 4) + c];
        fk_s[row][c] = feat4[(k0 + row) * (DF / 4) + c];
    }
    __syncthreads();

    const int ii = t >> 4, kk = t & 15;
    float sq = 0.f;
#pragma unroll
    for (int d = 0; d < DF / 4; ++d) {
        float4 a = fi_s[ii][d];
        float4 b = fk_s[kk][d];
        float dx = a.x - b.x, dy = a.y - b.y, dz = a.z - b.z, dw = a.w - b.w;
        sq += dx * dx + dy * dy + dz * dz + dw * dw;
    }
    const int gi = i0 + ii, gk = k0 + kk;
    float dist = (sq > 0.f) ? sqrtf(sq) : 0.f;
    float lo = -dist * (1.0f / TEMP);
    float eo = (gi == gk) ? 0.f : expf(lo);

    float4 ha = hi_s[ii], hb = hk_s[kk];
    float s = 0.f;
    {
        float d0 = ha.x - hb.x, d1 = ha.y - hb.y, d2 = ha.z - hb.z;
        float a0 = fabsf(d0), a1 = fabsf(d1), a2 = fabsf(d2);
        s += (a0 < BETA) ? (0.5f * d0 * d0 / BETA) : (a0 - 0.5f * BETA);
        s += (a1 < BETA) ? (0.5f * d1 * d1 / BETA) : (a1 - 0.5f * BETA);
        s += (a2 < BETA) ? (0.5f * d2 * d2 / BETA) : (a2 - 0.5f * BETA);
    }
    float td = s * (1.0f / 3.0f);

    float4 ga = gi_s[ii], gb = gk_s[kk];
    float gdiff = 1.0f - (ga.x * gb.x + ga.y * gb.y + ga.z * gb.z) / (ga.w * gb.w);
    float4 ra = ri_s[ii], rb = rk_s[kk];
    float rdiff = 1.0f - (ra.x * rb.x + ra.y * rb.y + ra.z * rb.z) / (ra.w * rb.w);
    bool pair_sym = (ha.w != 0.f) || (hb.w != 0.f);
    float rd = pair_sym ? gdiff : (gdiff + rdiff);

    pk[gi * N + gk] = make_float4(td, rd, eo, lo);
}

// ---------------------------------------------------------------------------
// Kernel B: rank denominators + pos terms. 768 blocks (row i = b>>1, j-half
// h = b&1) x 512 threads (8 waves). Lane l holds 3 j's in registers; wave w
// covers k in [w*48, w*48+48). One broadcast ds_read_b128 per k serves 6
// accumulator chains. 24 waves of work per CU for latency hiding.
// ---------------------------------------------------------------------------
__global__ __launch_bounds__(512) void rnc_rank(
    const float4* __restrict__ pk,
    float* __restrict__ partial_h,    // [768]
    float* __restrict__ partial_t)    // [768]
{
    const int i = blockIdx.x >> 1;
    const int h = blockIdx.x & 1;
    const int t = threadIdx.x;

    __shared__ __align__(16) float4 pks[N];      // 6 KB
    __shared__ __align__(16) float2 dp[192][8];  // 12 KB: [j_local][wave]
    __shared__ float red_h[8], red_t[8];

    if (t < N) pks[t] = pk[i * N + t];
    __syncthreads();

    const int w = t >> 6, l = t & 63;
    const int jl = l * 3;                 // local j base 0..189
    float tdj[3], rdj[3];
    float dent[3] = {0.f, 0.f, 0.f};
    float denh[3] = {0.f, 0.f, 0.f};
#pragma unroll
    for (int jj = 0; jj < 3; ++jj) {
        float4 p = pks[h * 192 + jl + jj];
        tdj[jj] = p.x;
        rdj[jj] = p.y;
    }
    const int k0 = w * 48;
#pragma unroll 4
    for (int k = k0; k < k0 + 48; ++k) {
        float4 p = pks[k];  // wave-uniform -> broadcast
#pragma unroll
        for (int jj = 0; jj < 3; ++jj) {
            bool mt = p.x >= tdj[jj];
            bool mh = mt && (p.y >= rdj[jj]);
            dent[jj] += mt ? p.z : 0.f;
            denh[jj] += mh ? p.z : 0.f;
        }
    }
#pragma unroll
    for (int jj = 0; jj < 3; ++jj) dp[jl + jj][w] = make_float2(dent[jj], denh[jj]);
    __syncthreads();

    float pos_h = 0.f, pos_t = 0.f;
    if (t < 192) {
        const int j = h * 192 + t;
        if (j != i) {
            float st_ = 0.f, sh_ = 0.f;
#pragma unroll
            for (int g = 0; g < 8; ++g) {
                float2 v = dp[t][g];
                st_ += v.x;
                sh_ += v.y;
            }
            float lo = pks[j].w;
            pos_h = lo - logf(sh_ + EPS_LOG);
            pos_t = lo - logf(st_ + EPS_LOG);
        }
    }
#pragma unroll
    for (int off = 32; off > 0; off >>= 1) {
        pos_h += __shfl_down(pos_h, off, 64);
        pos_t += __shfl_down(pos_t, off, 64);
    }
    if (l == 0) {
        red_h[w] = pos_h;
        red_t[w] = pos_t;
    }
    __syncthreads();
    if (t == 0) {
        float sh = 0.f, st = 0.f;
#pragma unroll
        for (int g = 0; g < 8; ++g) {
            sh += red_h[g];
            st += red_t[g];
        }
        partial_h[blockIdx.x] = sh;
        partial_t[blockIdx.x] = st;
    }
}

__global__ __launch_bounds__(768) void rnc_final(
    const float* __restrict__ partial_h,
    const float* __restrict__ partial_t,
    float* __restrict__ out)
{
    const int t = threadIdx.x;
    float hsum = partial_h[t];
    float tsum = partial_t[t];
#pragma unroll
    for (int off = 32; off > 0; off >>= 1) {
        hsum += __shfl_down(hsum, off, 64);
        tsum += __shfl_down(tsum, off, 64);
    }
    __shared__ float rh[12], rt[12];
    const int wave = t >> 6, lane = t & 63;
    if (lane == 0) {
        rh[wave] = hsum;
        rt[wave] = tsum;
    }
    __syncthreads();
    if (t == 0) {
        double sh = 0.0, st = 0.0;
#pragma unroll
        for (int w = 0; w < 12; ++w) {
            sh += (double)rh[w];
            st += (double)rt[w];
        }
        const double denom = (double)N * (double)(N - 1);
        out[0] = (float)(-(sh + (double)SOFT_LAMBDA * st) / denom);
    }
}

extern "C" void kernel_launch(void* const* d_in, const int* in_sizes, int n_in,
                              void* d_out, int out_size, void* d_ws, size_t ws_size,
                              hipStream_t stream) {
    const float* feat = (const float*)d_in[0];  // [384,128]
    const float* rg   = (const float*)d_in[1];  // [384,3]
    const float* rr   = (const float*)d_in[2];  // [384,3]
    const float* tr   = (const float*)d_in[3];  // [384,3]
    const int*   sym  = (const int*)d_in[4];    // [384,1]
    float* out = (float*)d_out;

    float4* pk = (float4*)d_ws;                                   // 384*384*16 B
    float* partial_h = (float*)((char*)d_ws + (size_t)N * N * sizeof(float4));
    float* partial_t = partial_h + 2 * N;

    dim3 gridA(N / TK, N / TI);
    rnc_pairs<<<gridA, 256, 0, stream>>>(feat, rg, rr, tr, sym, pk);
    rnc_rank<<<2 * N, 512, 0, stream>>>(pk, partial_h, partial_t);
    rnc_final<<<1, 2 * N, 0, stream>>>(partial_h, partial_t, out);
}